// Round 12
// baseline (967.729 us; speedup 1.0000x reference)
//
#include <hip/hip_runtime.h>
#include <math.h>

#define MM 100     // mentions
#define CC 30      // candidates
#define DE 300     // embedding dim
#define NK 3       // relation types
#define NLOOP 10   // LBP iterations
#define INV_SQRT_D 0.05773502691896258f   // 1/sqrt(300)

typedef __attribute__((ext_vector_type(8))) short bf16x8;
typedef __attribute__((ext_vector_type(4))) float f32x4;

// ws layout (floats):
//  f@0 psi@60000 t@63000 a@153000
//  REH@183000 REL@1719000 (bf16 [k][i][32][320] padded hi/lo)
//  entH@3255000 entL@3767000 (bf16 [j][32][320])
//  phi@4279000  mbarA@13279000 mbarB@13579000 stotbuf@13879000 (11*3000)

__device__ inline void bf16split(float x, short* hi, short* lo) {
  unsigned u  = __float_as_uint(x);
  unsigned hu = u & 0xFFFF0000u;
  float xh = __uint_as_float(hu);
  float rl = x - xh;
  unsigned lu = __float_as_uint(rl);
  lu += 0x7FFFu + ((lu >> 16) & 1u);
  *hi = (short)(hu >> 16);
  *lo = (short)(lu >> 16);
}

// ---------- fused front, parallelism-fixed ----------
// f-stage: wave = e-chunk (225), lanes over d (coalesced W rows), LDS-reduce.
// g/t-stages: wave-per-dot, lanes over e (coalesced B/D rows), shuffle-reduce.
__global__ __launch_bounds__(256) void k_front(const float* __restrict__ fmc,
                                               const float* __restrict__ W,
                                               const float* __restrict__ b,
                                               const float* __restrict__ Bm,
                                               const float* __restrict__ Dm,
                                               const float* __restrict__ ent,
                                               float* __restrict__ f,
                                               float* __restrict__ psi,
                                               float* __restrict__ t) {
  __shared__ float xs[3*DE];
  __shared__ float fs[DE];
  __shared__ float gs[DE];
  __shared__ float part[4][304];
  const int m = blockIdx.x;
  const int wave = threadIdx.x >> 6, lane = threadIdx.x & 63;

  for (int e = threadIdx.x; e < 3*DE; e += 256) xs[e] = fmc[m*3*DE + e];
  __syncthreads();

  // ---- f partials ----
  {
    float acc[5];
    #pragma unroll
    for (int dg = 0; dg < 5; ++dg) acc[dg] = 0.f;
    const int e0 = wave*225, e1 = e0 + 225;
    for (int e = e0; e < e1; ++e) {
      const float xv = xs[e];
      const float* Wr = W + e*DE;
      #pragma unroll
      for (int dg = 0; dg < 5; ++dg) {
        const int d = lane + dg*64;
        const float wv = (d < DE) ? Wr[d] : 0.f;
        acc[dg] = fmaf(xv, wv, acc[dg]);
      }
    }
    #pragma unroll
    for (int dg = 0; dg < 5; ++dg) {
      const int d = lane + dg*64;
      if (d < DE) part[wave][d] = acc[dg];
    }
  }
  __syncthreads();
  for (int d = threadIdx.x; d < DE; d += 256) {
    float v = part[0][d] + part[1][d] + part[2][d] + part[3][d] + b[d];
    v = tanhf(v);
    fs[d] = v;
    f[m*DE + d] = v;
  }
  __syncthreads();

  // ---- g: gs[d] = Bm[d,:]·fs (wave-per-dot, coalesced) ----
  for (int d = wave; d < DE; d += 4) {
    const float* Br = Bm + d*DE;
    float acc = 0.f;
    for (int e = lane; e < DE; e += 64) acc = fmaf(Br[e], fs[e], acc);
    #pragma unroll
    for (int off = 32; off; off >>= 1) acc += __shfl_down(acc, off, 64);
    if (lane == 0) gs[d] = acc;
  }
  // ---- t: t[k,m,d] = Dm[k,d,:]·fs ----
  for (int kd = wave; kd < NK*DE; kd += 4) {
    const float* Dr = Dm + kd*DE;
    float acc = 0.f;
    for (int e = lane; e < DE; e += 64) acc = fmaf(Dr[e], fs[e], acc);
    #pragma unroll
    for (int off = 32; off; off >>= 1) acc += __shfl_down(acc, off, 64);
    if (lane == 0) {
      const int k = kd / DE, d = kd % DE;
      t[(k*MM + m)*DE + d] = acc;
    }
  }
  __syncthreads();

  // ---- psi[m,c] = ent[m,c,:]·gs ----
  for (int c = wave; c < CC; c += 4) {
    float acc = 0.f;
    const float* er = ent + (m*CC + c)*DE;
    for (int d = lane; d < DE; d += 64) acc = fmaf(er[d], gs[d], acc);
    #pragma unroll
    for (int off = 32; off; off >>= 1) acc += __shfl_down(acc, off, 64);
    if (lane == 0) psi[m*CC + c] = acc;
  }
}

// ---------- a[i,j,k] = softmax_k( f_i . t[k,j,:] / sqrt(D) ) ----------
__global__ __launch_bounds__(256) void k_a(const float* __restrict__ f,
                                           const float* __restrict__ t,
                                           float* __restrict__ a) {
  __shared__ float fs[DE];
  int i = blockIdx.x;
  for (int e = threadIdx.x; e < DE; e += 256) fs[e] = f[i*DE + e];
  __syncthreads();
  int wave = threadIdx.x >> 6, lane = threadIdx.x & 63;
  for (int j = wave; j < MM; j += 4) {
    float sk[NK];
    #pragma unroll
    for (int k = 0; k < NK; ++k) {
      float acc = 0.f;
      const float* tr = t + (k*MM + j)*DE;
      for (int d = lane; d < DE; d += 64) acc = fmaf(fs[d], tr[d], acc);
      #pragma unroll
      for (int off = 32; off; off >>= 1) acc += __shfl_down(acc, off, 64);
      sk[k] = acc;
    }
    if (lane == 0) {
      float s0 = sk[0]*INV_SQRT_D, s1 = sk[1]*INV_SQRT_D, s2 = sk[2]*INV_SQRT_D;
      float mx = fmaxf(s0, fmaxf(s1, s2));
      float e0 = expf(s0 - mx), e1 = expf(s1 - mx), e2 = expf(s2 - mx);
      float inv = 1.f / (e0 + e1 + e2);
      float* ar = a + (i*MM + j)*NK;
      ar[0] = e0*inv; ar[1] = e1*inv; ar[2] = e2*inv;
    }
  }
}

// ---------- split ent -> padded bf16 hi/lo [j][32][320] ----------
__global__ __launch_bounds__(256) void k_esplit(const float* __restrict__ ent,
                                                short* __restrict__ entH,
                                                short* __restrict__ entL) {
  int j = blockIdx.x;
  for (int idx = threadIdx.x; idx < 32*320; idx += 256) {
    int q = idx / 320, kk = idx % 320;
    float x = (q < CC && kk < DE) ? ent[(j*CC + q)*DE + kk] : 0.f;
    short h, l;
    bf16split(x, &h, &l);
    entH[(j*32 + q)*320 + kk] = h;
    entL[(j*32 + q)*320 + kk] = l;
  }
}

// ---------- RE GEMM: out = split_bf16( ent_flat[3000,300] @ R_k^T ), padded ----------
__global__ __launch_bounds__(256) void k_re(const float* __restrict__ R,
                                            const float* __restrict__ ent,
                                            short* __restrict__ REH,
                                            short* __restrict__ REL) {
  __shared__ float4 As4[128*5];
  __shared__ float4 Bs4[64*5];
  float* As = (float*)As4;
  float* Bs = (float*)Bs4;

  const int k  = blockIdx.z;
  const int r0 = blockIdx.y * 128;
  const int d0 = blockIdx.x * 64;
  const int tx = threadIdx.x & 15;
  const int ty = threadIdx.x >> 4;
  const float* A  = ent;
  const float* Bk = R + k*DE*DE;

  float acc[8][4];
  #pragma unroll
  for (int r = 0; r < 8; ++r)
    #pragma unroll
    for (int s = 0; s < 4; ++s) acc[r][s] = 0.f;

  for (int e0 = 0; e0 < DE; e0 += 20) {
    #pragma unroll
    for (int it = 0; it < 10; ++it) {
      int idx = threadIdx.x + it*256;
      int row = idx / 20, e = idx % 20;
      int gr = r0 + row;
      As[idx] = (gr < MM*CC) ? A[gr*DE + e0 + e] : 0.f;
    }
    #pragma unroll
    for (int it = 0; it < 5; ++it) {
      int idx = threadIdx.x + it*256;
      int row = idx / 20, e = idx % 20;
      int gd = d0 + row;
      Bs[idx] = (gd < DE) ? Bk[gd*DE + e0 + e] : 0.f;
    }
    __syncthreads();

    #pragma unroll
    for (int v = 0; v < 5; ++v) {
      float4 av[8], bv[4];
      #pragma unroll
      for (int r = 0; r < 8; ++r) av[r] = As4[(ty + 16*r)*5 + v];
      #pragma unroll
      for (int s = 0; s < 4; ++s) bv[s] = Bs4[(tx + 16*s)*5 + v];
      #pragma unroll
      for (int r = 0; r < 8; ++r)
        #pragma unroll
        for (int s = 0; s < 4; ++s) {
          acc[r][s] = fmaf(av[r].x, bv[s].x, acc[r][s]);
          acc[r][s] = fmaf(av[r].y, bv[s].y, acc[r][s]);
          acc[r][s] = fmaf(av[r].z, bv[s].z, acc[r][s]);
          acc[r][s] = fmaf(av[r].w, bv[s].w, acc[r][s]);
        }
    }
    __syncthreads();
  }

  #pragma unroll
  for (int r = 0; r < 8; ++r) {
    int gr = r0 + ty + 16*r;
    if (gr < MM*CC) {
      int i = gr / CC, p = gr % CC;
      #pragma unroll
      for (int s = 0; s < 4; ++s) {
        int gd = d0 + tx + 16*s;
        if (gd < DE) {
          size_t idx = (((size_t)k*MM + i)*32 + p)*320 + gd;
          short h, l;
          bf16split(acc[r][s], &h, &l);
          REH[idx] = h;
          REL[idx] = l;
        }
      }
    }
  }
}

// ---------- phi via MFMA: LDS-staged A (R11-verified k_phi6, frozen) ----------
__global__ __launch_bounds__(256) void k_phi6(const float* __restrict__ a,
                                              const short* __restrict__ REH,
                                              const short* __restrict__ REL,
                                              const short* __restrict__ entH,
                                              const short* __restrict__ entL,
                                              float* __restrict__ phi) {
  __shared__ short As[2][12*512];   // 24,576 B
  const int bs = blockIdx.x;
  int i, jg;
  if (bs < 2400) {
    int x = bs & 7;
    int s = bs >> 3;
    jg = s / 12;
    i  = x*12 + s % 12;
  } else {
    int r = bs - 2400;
    i  = 96 + (r & 3);
    jg = r >> 2;
  }
  const int wave = threadIdx.x >> 6;
  const int lane = threadIdx.x & 63;
  const int j = jg*4 + wave;

  const int row = lane & 15;
  const int g8  = (lane >> 4) << 3;

  const float a0 = a[(i*MM + j)*NK + 0];
  const float a1 = a[(i*MM + j)*NK + 1];
  const float a2 = a[(i*MM + j)*NK + 2];

  const int b0 = (j*32 + row)*320;
  const int b1 = b0 + 16*320;

  const short* asrc[3];
  short* adst[3];
  #pragma unroll
  for (int q = 0; q < 3; ++q) {
    const int fr = 3*wave + q;
    const int b6 = fr % 6;
    const int kr = b6 >> 1, rb = b6 & 1;
    const short* src = (fr < 6) ? REH : REL;
    asrc[q] = src + ((kr*MM + i)*32 + rb*16 + row)*320 + g8;
    adst[q] = (short*)As + fr*512 + lane*8;
  }

  f32x4 acc[3][2][2];
  #pragma unroll
  for (int kr = 0; kr < 3; ++kr)
    #pragma unroll
    for (int r = 0; r < 2; ++r)
      #pragma unroll
      for (int s = 0; s < 2; ++s)
        acc[kr][r][s] = (f32x4){0.f, 0.f, 0.f, 0.f};

  {
    int4 v0 = *(const int4*)(asrc[0]);
    int4 v1 = *(const int4*)(asrc[1]);
    int4 v2 = *(const int4*)(asrc[2]);
    *(int4*)(adst[0]) = v0;
    *(int4*)(adst[1]) = v1;
    *(int4*)(adst[2]) = v2;
  }
  __syncthreads();

  int cur = 0;
  for (int c = 0; c < 10; ++c) {
    int4 v0, v1, v2;
    if (c < 9) {
      v0 = *(const int4*)(asrc[0] + (c+1)*32);
      v1 = *(const int4*)(asrc[1] + (c+1)*32);
      v2 = *(const int4*)(asrc[2] + (c+1)*32);
    }
    const int kk = c*32 + g8;
    bf16x8 BH0 = *(const bf16x8*)(entH + b0 + kk);
    bf16x8 BH1 = *(const bf16x8*)(entH + b1 + kk);
    bf16x8 BL0 = *(const bf16x8*)(entL + b0 + kk);
    bf16x8 BL1 = *(const bf16x8*)(entL + b1 + kk);

    const short* Ab = (const short*)As + cur*12*512 + lane*8;
    #pragma unroll
    for (int kr = 0; kr < 3; ++kr) {
      bf16x8 AH0 = *(const bf16x8*)(Ab + (kr*2 + 0)*512);
      bf16x8 AH1 = *(const bf16x8*)(Ab + (kr*2 + 1)*512);
      bf16x8 AL0 = *(const bf16x8*)(Ab + (6 + kr*2 + 0)*512);
      bf16x8 AL1 = *(const bf16x8*)(Ab + (6 + kr*2 + 1)*512);
      acc[kr][0][0] = __builtin_amdgcn_mfma_f32_16x16x32_bf16(AH0, BH0, acc[kr][0][0], 0, 0, 0);
      acc[kr][0][0] = __builtin_amdgcn_mfma_f32_16x16x32_bf16(AH0, BL0, acc[kr][0][0], 0, 0, 0);
      acc[kr][0][0] = __builtin_amdgcn_mfma_f32_16x16x32_bf16(AL0, BH0, acc[kr][0][0], 0, 0, 0);
      acc[kr][0][1] = __builtin_amdgcn_mfma_f32_16x16x32_bf16(AH0, BH1, acc[kr][0][1], 0, 0, 0);
      acc[kr][0][1] = __builtin_amdgcn_mfma_f32_16x16x32_bf16(AH0, BL1, acc[kr][0][1], 0, 0, 0);
      acc[kr][0][1] = __builtin_amdgcn_mfma_f32_16x16x32_bf16(AL0, BH1, acc[kr][0][1], 0, 0, 0);
      acc[kr][1][0] = __builtin_amdgcn_mfma_f32_16x16x32_bf16(AH1, BH0, acc[kr][1][0], 0, 0, 0);
      acc[kr][1][0] = __builtin_amdgcn_mfma_f32_16x16x32_bf16(AH1, BL0, acc[kr][1][0], 0, 0, 0);
      acc[kr][1][0] = __builtin_amdgcn_mfma_f32_16x16x32_bf16(AL1, BH0, acc[kr][1][0], 0, 0, 0);
      acc[kr][1][1] = __builtin_amdgcn_mfma_f32_16x16x32_bf16(AH1, BH1, acc[kr][1][1], 0, 0, 0);
      acc[kr][1][1] = __builtin_amdgcn_mfma_f32_16x16x32_bf16(AH1, BL1, acc[kr][1][1], 0, 0, 0);
      acc[kr][1][1] = __builtin_amdgcn_mfma_f32_16x16x32_bf16(AL1, BH1, acc[kr][1][1], 0, 0, 0);
    }

    if (c < 9) {
      short* dst = (short*)As + (cur^1)*12*512;
      *(int4*)(dst + (3*wave + 0)*512 + lane*8) = v0;
      *(int4*)(dst + (3*wave + 1)*512 + lane*8) = v1;
      *(int4*)(dst + (3*wave + 2)*512 + lane*8) = v2;
      __syncthreads();
      cur ^= 1;
    }
  }

  float* ph = phi + (i*MM + j)*CC*CC;
  const int rbase = (lane >> 4) * 4;
  #pragma unroll
  for (int r = 0; r < 2; ++r) {
    #pragma unroll
    for (int t = 0; t < 4; ++t) {
      const int p = 16*r + rbase + t;
      if (p < CC) {
        #pragma unroll
        for (int s = 0; s < 2; ++s) {
          const int q = 16*s + row;
          if (q < CC) {
            float v = a0*acc[0][r][s][t] + a1*acc[1][r][s][t] + a2*acc[2][r][s][t];
            ph[p*CC + q] = v;
          }
        }
      }
    }
  }
}

// ---------- zero ----------
__global__ void k_zero(float* __restrict__ p, int n) {
  int idx = blockIdx.x*256 + threadIdx.x;
  if (idx < n) p[idx] = 0.f;
}

// ---------- damped LBP update + fused stot (atomics), XCD-pinned i-slices ----------
// grid 2600: x = bs&7 (XCD) owns i in [13x, 13x+13) -> 4.7 MB phi slice per
// XCD L2, re-read each iteration instead of streaming all 36 MB cross-die.
__global__ __launch_bounds__(256) void k_up4(const float* __restrict__ phi,
                                             const float* __restrict__ psi,
                                             const float* __restrict__ stot_cur,
                                             float* __restrict__ stot_next,
                                             const float* __restrict__ mb_old,
                                             float* __restrict__ mb_new) {
  const int x = blockIdx.x & 7;
  const int r = blockIdx.x >> 3;      // 0..324
  const int i = x*13 + (r % 13);
  const int jg = r / 13;              // 0..24
  if (i >= MM) return;
  const int wave = threadIdx.x >> 6;
  const int lane = threadIdx.x & 63;
  const int j = jg*4 + wave;
  const int half = lane >> 5;
  const int q = lane & 31;

  __shared__ float psi_st[32];
  if (threadIdx.x < CC)
    psi_st[threadIdx.x] = psi[i*CC + threadIdx.x] + stot_cur[i*CC + threadIdx.x];
  __syncthreads();

  float csr = (q < CC) ? psi_st[q] - mb_old[(j*MM + i)*CC + q] : -1e30f;

  const float* ph = phi + (i*MM + j)*CC*CC;
  float mv = -1e30f;
  const int p0 = half * 15;
  #pragma unroll
  for (int pp = 0; pp < 15; ++pp) {
    const int p = p0 + pp;
    float v = (q < CC) ? ph[p*CC + q] : -1e30f;
    float cv = __shfl(csr, p, 64);
    mv = fmaxf(mv, v + cv);
  }
  mv = fmaxf(mv, __shfl_xor(mv, 32, 64));
  float xx = (q < CC) ? fmaxf(mv, 0.f) : -1e30f;

  float mx = xx;
  #pragma unroll
  for (int off = 16; off; off >>= 1) mx = fmaxf(mx, __shfl_xor(mx, off, 64));
  float e = (q < CC) ? expf(xx - mx) : 0.f;
  float se = e;
  #pragma unroll
  for (int off = 16; off; off >>= 1) se += __shfl_xor(se, off, 64);

  if (lane < CC) {
    float sm = e / se;
    float old = mb_old[(i*MM + j)*CC + lane];
    float nv = logf(0.5f*expf(old) + 0.5f*sm);
    mb_new[(i*MM + j)*CC + lane] = nv;
    atomicAdd(stot_next + j*CC + lane, nv);
  }
}

// ---------- out[i,:] = softmax( psi + stot_final[i,:] - mbar[i,i,:] ) ----------
__global__ __launch_bounds__(64) void k_final(const float* __restrict__ psi,
                                              const float* __restrict__ stotN,
                                              const float* __restrict__ mb,
                                              float* __restrict__ out) {
  int i = blockIdx.x;
  int lane = threadIdx.x;
  float x = -1e30f;
  if (lane < CC)
    x = psi[i*CC + lane] + stotN[i*CC + lane] - mb[(i*MM + i)*CC + lane];
  float mx = x;
  #pragma unroll
  for (int off = 16; off; off >>= 1) mx = fmaxf(mx, __shfl_xor(mx, off, 32));
  float e = (lane < CC) ? expf(x - mx) : 0.f;
  float se = e;
  #pragma unroll
  for (int off = 16; off; off >>= 1) se += __shfl_xor(se, off, 32);
  if (lane < CC) out[i*CC + lane] = e / se;
}

extern "C" void kernel_launch(void* const* d_in, const int* in_sizes, int n_in,
                              void* d_out, int out_size, void* d_ws, size_t ws_size,
                              hipStream_t stream) {
  (void)in_sizes; (void)n_in; (void)out_size; (void)ws_size;
  const float* ent  = (const float*)d_in[0];
  const float* fmc  = (const float*)d_in[1];
  const float* W    = (const float*)d_in[2];
  const float* b    = (const float*)d_in[3];
  const float* Bm   = (const float*)d_in[4];
  const float* R    = (const float*)d_in[5];
  const float* Dm   = (const float*)d_in[6];
  float* out = (float*)d_out;
  float* ws  = (float*)d_ws;

  float* f    = ws + 0;
  float* psi  = ws + 60000;
  float* t    = ws + 63000;
  float* a    = ws + 153000;
  short* REH  = (short*)(ws + 183000);
  short* REL  = (short*)(ws + 1719000);
  short* entH = (short*)(ws + 3255000);
  short* entL = (short*)(ws + 3767000);
  float* phi  = ws + 4279000;
  float* mbA  = ws + 13279000;
  float* mbB  = ws + 13579000;
  float* stotbuf = ws + 13879000;   // (NLOOP+1)*3000 floats

  k_zero<<<(633000 + 255)/256, 256, 0, stream>>>(mbA, 633000);
  k_zero<<<(3072000 + 255)/256, 256, 0, stream>>>(ws + 183000, 3072000);  // RE pads

  k_front<<<MM, 256, 0, stream>>>(fmc, W, b, Bm, Dm, ent, f, psi, t);
  k_a    <<<MM, 256, 0, stream>>>(f, t, a);
  k_esplit<<<MM, 256, 0, stream>>>(ent, entH, entL);
  {
    dim3 grid(5, 24, 3);
    k_re<<<grid, 256, 0, stream>>>(R, ent, REH, REL);
  }
  k_phi6<<<2500, 256, 0, stream>>>(a, REH, REL, entH, entL, phi);

  float* cur = mbA; float* nxt = mbB;
  for (int it = 0; it < NLOOP; ++it) {
    k_up4<<<2600, 256, 0, stream>>>(phi, psi,
                                    stotbuf + it*MM*CC,
                                    stotbuf + (it+1)*MM*CC,
                                    cur, nxt);
    float* tmp = cur; cur = nxt; nxt = tmp;
  }
  k_final<<<MM, 64, 0, stream>>>(psi, stotbuf + NLOOP*MM*CC, cur, out);
}

// Round 13
// 551.547 us; speedup vs baseline: 1.7546x; 1.7546x over previous
//
#include <hip/hip_runtime.h>
#include <math.h>

#define MM 100     // mentions
#define CC 30      // candidates
#define DE 300     // embedding dim
#define NK 3       // relation types
#define NLOOP 10   // LBP iterations
#define INV_SQRT_D 0.05773502691896258f   // 1/sqrt(300)

typedef __attribute__((ext_vector_type(8))) short bf16x8;
typedef __attribute__((ext_vector_type(4))) float f32x4;

// ws layout (floats):
//  f@0 psi@60000 t@63000 a@153000
//  REH@183000 REL@1719000 (bf16 [k][i][32][320] padded hi/lo)
//  entH@3255000 entL@3767000 (bf16 [j][32][320])
//  phi@4279000  mbarA@13279000 mbarB@13579000 stotbuf@13879000 (11*3000)
//  g stash: transient at ws+183000 (REH area; consumed by k_psi before k_re)

__device__ inline void bf16split(float x, short* hi, short* lo) {
  unsigned u  = __float_as_uint(x);
  unsigned hu = u & 0xFFFF0000u;
  float xh = __uint_as_float(hu);
  float rl = x - xh;
  unsigned lu = __float_as_uint(rl);
  lu += 0x7FFFu + ((lu >> 16) & 1u);
  *hi = (short)(hu >> 16);
  *lo = (short)(lu >> 16);
}

// ---------- f partial GEMV: 1200 blocks (m x 12 e-chunks of 75), atomic ----------
__global__ __launch_bounds__(256) void k_f1(const float* __restrict__ fmc,
                                            const float* __restrict__ W,
                                            const float* __restrict__ b,
                                            float* __restrict__ f) {
  __shared__ float xs[75];
  const int m  = blockIdx.x / 12;
  const int eq = blockIdx.x % 12;
  const int e0 = eq * 75;
  const int tid = threadIdx.x;
  for (int e = tid; e < 75; e += 256) xs[e] = fmc[m*3*DE + e0 + e];
  __syncthreads();

  const int d0 = tid;            // < 300 always
  const int d1 = tid + 256;      // valid if < 300 (tid < 44)
  float acc0 = 0.f, acc1 = 0.f;
  for (int e = 0; e < 75; ++e) {
    const float xv = xs[e];
    const float* Wr = W + (e0 + e)*DE;
    acc0 = fmaf(xv, Wr[d0], acc0);
    if (d1 < DE) acc1 = fmaf(xv, Wr[d1], acc1);
  }
  if (eq == 0) {
    acc0 += b[d0];
    if (d1 < DE) acc1 += b[d1];
  }
  atomicAdd(f + m*DE + d0, acc0);
  if (d1 < DE) atomicAdd(f + m*DE + d1, acc1);
}

// ---------- elementwise tanh over f ----------
__global__ void k_tanh(float* __restrict__ f, int n) {
  int idx = blockIdx.x*256 + threadIdx.x;
  if (idx < n) f[idx] = tanhf(f[idx]);
}

// ---------- g & t: wave-per-dot over stacked [B; D] rows, 1900 blocks ----------
// cols 0..299 -> g[m,col]; cols 300..1199 -> t[(k*MM+m)*DE+d], k=(col-300)/300
__global__ __launch_bounds__(256) void k_gt(const float* __restrict__ Bm,
                                            const float* __restrict__ Dm,
                                            const float* __restrict__ f,
                                            float* __restrict__ gst,
                                            float* __restrict__ t) {
  __shared__ float fs[DE];
  const int m  = blockIdx.x / 19;
  const int cg = blockIdx.x % 19;
  const int wave = threadIdx.x >> 6, lane = threadIdx.x & 63;
  for (int e = threadIdx.x; e < DE; e += 256) fs[e] = f[m*DE + e];
  __syncthreads();

  #pragma unroll
  for (int u = 0; u < 16; ++u) {
    const int col = cg*64 + wave*16 + u;
    const bool ok = (col < 1200);
    const int ccl = ok ? col : 0;
    const float* row = (ccl < DE) ? (Bm + ccl*DE) : (Dm + (ccl - DE)*DE);
    float acc = 0.f;
    for (int e = lane; e < DE; e += 64) acc = fmaf(row[e], fs[e], acc);
    #pragma unroll
    for (int off = 32; off; off >>= 1) acc += __shfl_down(acc, off, 64);
    if (ok && lane == 0) {
      if (col < DE) {
        gst[m*DE + col] = acc;
      } else {
        const int k = (col - DE) / DE, d = (col - DE) % DE;
        t[(k*MM + m)*DE + d] = acc;
      }
    }
  }
}

// ---------- psi[m,c] = ent[m,c,:] . g[m,:] ----------
__global__ __launch_bounds__(256) void k_psi(const float* __restrict__ ent,
                                             const float* __restrict__ gst,
                                             float* __restrict__ psi) {
  __shared__ float gs[DE];
  int m = blockIdx.x;
  for (int e = threadIdx.x; e < DE; e += 256) gs[e] = gst[m*DE + e];
  __syncthreads();
  int wave = threadIdx.x >> 6, lane = threadIdx.x & 63;
  for (int c = wave; c < CC; c += 4) {
    float acc = 0.f;
    const float* er = ent + (m*CC + c)*DE;
    for (int d = lane; d < DE; d += 64) acc = fmaf(er[d], gs[d], acc);
    #pragma unroll
    for (int off = 32; off; off >>= 1) acc += __shfl_down(acc, off, 64);
    if (lane == 0) psi[m*CC + c] = acc;
  }
}

// ---------- a[i,j,k] = softmax_k( f_i . t[k,j,:] / sqrt(D) ) ----------
__global__ __launch_bounds__(256) void k_a(const float* __restrict__ f,
                                           const float* __restrict__ t,
                                           float* __restrict__ a) {
  __shared__ float fs[DE];
  int i = blockIdx.x;
  for (int e = threadIdx.x; e < DE; e += 256) fs[e] = f[i*DE + e];
  __syncthreads();
  int wave = threadIdx.x >> 6, lane = threadIdx.x & 63;
  for (int j = wave; j < MM; j += 4) {
    float sk[NK];
    #pragma unroll
    for (int k = 0; k < NK; ++k) {
      float acc = 0.f;
      const float* tr = t + (k*MM + j)*DE;
      for (int d = lane; d < DE; d += 64) acc = fmaf(fs[d], tr[d], acc);
      #pragma unroll
      for (int off = 32; off; off >>= 1) acc += __shfl_down(acc, off, 64);
      sk[k] = acc;
    }
    if (lane == 0) {
      float s0 = sk[0]*INV_SQRT_D, s1 = sk[1]*INV_SQRT_D, s2 = sk[2]*INV_SQRT_D;
      float mx = fmaxf(s0, fmaxf(s1, s2));
      float e0 = expf(s0 - mx), e1 = expf(s1 - mx), e2 = expf(s2 - mx);
      float inv = 1.f / (e0 + e1 + e2);
      float* ar = a + (i*MM + j)*NK;
      ar[0] = e0*inv; ar[1] = e1*inv; ar[2] = e2*inv;
    }
  }
}

// ---------- split ent -> padded bf16 hi/lo [j][32][320] ----------
__global__ __launch_bounds__(256) void k_esplit(const float* __restrict__ ent,
                                                short* __restrict__ entH,
                                                short* __restrict__ entL) {
  int j = blockIdx.x;
  for (int idx = threadIdx.x; idx < 32*320; idx += 256) {
    int q = idx / 320, kk = idx % 320;
    float x = (q < CC && kk < DE) ? ent[(j*CC + q)*DE + kk] : 0.f;
    short h, l;
    bf16split(x, &h, &l);
    entH[(j*32 + q)*320 + kk] = h;
    entL[(j*32 + q)*320 + kk] = l;
  }
}

// ---------- RE GEMM: out = split_bf16( ent_flat[3000,300] @ R_k^T ), padded ----------
__global__ __launch_bounds__(256) void k_re(const float* __restrict__ R,
                                            const float* __restrict__ ent,
                                            short* __restrict__ REH,
                                            short* __restrict__ REL) {
  __shared__ float4 As4[128*5];
  __shared__ float4 Bs4[64*5];
  float* As = (float*)As4;
  float* Bs = (float*)Bs4;

  const int k  = blockIdx.z;
  const int r0 = blockIdx.y * 128;
  const int d0 = blockIdx.x * 64;
  const int tx = threadIdx.x & 15;
  const int ty = threadIdx.x >> 4;
  const float* A  = ent;
  const float* Bk = R + k*DE*DE;

  float acc[8][4];
  #pragma unroll
  for (int r = 0; r < 8; ++r)
    #pragma unroll
    for (int s = 0; s < 4; ++s) acc[r][s] = 0.f;

  for (int e0 = 0; e0 < DE; e0 += 20) {
    #pragma unroll
    for (int it = 0; it < 10; ++it) {
      int idx = threadIdx.x + it*256;
      int row = idx / 20, e = idx % 20;
      int gr = r0 + row;
      As[idx] = (gr < MM*CC) ? A[gr*DE + e0 + e] : 0.f;
    }
    #pragma unroll
    for (int it = 0; it < 5; ++it) {
      int idx = threadIdx.x + it*256;
      int row = idx / 20, e = idx % 20;
      int gd = d0 + row;
      Bs[idx] = (gd < DE) ? Bk[gd*DE + e0 + e] : 0.f;
    }
    __syncthreads();

    #pragma unroll
    for (int v = 0; v < 5; ++v) {
      float4 av[8], bv[4];
      #pragma unroll
      for (int r = 0; r < 8; ++r) av[r] = As4[(ty + 16*r)*5 + v];
      #pragma unroll
      for (int s = 0; s < 4; ++s) bv[s] = Bs4[(tx + 16*s)*5 + v];
      #pragma unroll
      for (int r = 0; r < 8; ++r)
        #pragma unroll
        for (int s = 0; s < 4; ++s) {
          acc[r][s] = fmaf(av[r].x, bv[s].x, acc[r][s]);
          acc[r][s] = fmaf(av[r].y, bv[s].y, acc[r][s]);
          acc[r][s] = fmaf(av[r].z, bv[s].z, acc[r][s]);
          acc[r][s] = fmaf(av[r].w, bv[s].w, acc[r][s]);
        }
    }
    __syncthreads();
  }

  #pragma unroll
  for (int r = 0; r < 8; ++r) {
    int gr = r0 + ty + 16*r;
    if (gr < MM*CC) {
      int i = gr / CC, p = gr % CC;
      #pragma unroll
      for (int s = 0; s < 4; ++s) {
        int gd = d0 + tx + 16*s;
        if (gd < DE) {
          size_t idx = (((size_t)k*MM + i)*32 + p)*320 + gd;
          short h, l;
          bf16split(acc[r][s], &h, &l);
          REH[idx] = h;
          REL[idx] = l;
        }
      }
    }
  }
}

// ---------- phi via MFMA: LDS-staged A (R11-verified k_phi6, frozen) ----------
__global__ __launch_bounds__(256) void k_phi6(const float* __restrict__ a,
                                              const short* __restrict__ REH,
                                              const short* __restrict__ REL,
                                              const short* __restrict__ entH,
                                              const short* __restrict__ entL,
                                              float* __restrict__ phi) {
  __shared__ short As[2][12*512];   // 24,576 B
  const int bs = blockIdx.x;
  int i, jg;
  if (bs < 2400) {
    int x = bs & 7;
    int s = bs >> 3;
    jg = s / 12;
    i  = x*12 + s % 12;
  } else {
    int r = bs - 2400;
    i  = 96 + (r & 3);
    jg = r >> 2;
  }
  const int wave = threadIdx.x >> 6;
  const int lane = threadIdx.x & 63;
  const int j = jg*4 + wave;

  const int row = lane & 15;
  const int g8  = (lane >> 4) << 3;

  const float a0 = a[(i*MM + j)*NK + 0];
  const float a1 = a[(i*MM + j)*NK + 1];
  const float a2 = a[(i*MM + j)*NK + 2];

  const int b0 = (j*32 + row)*320;
  const int b1 = b0 + 16*320;

  const short* asrc[3];
  short* adst[3];
  #pragma unroll
  for (int q = 0; q < 3; ++q) {
    const int fr = 3*wave + q;
    const int b6 = fr % 6;
    const int kr = b6 >> 1, rb = b6 & 1;
    const short* src = (fr < 6) ? REH : REL;
    asrc[q] = src + ((kr*MM + i)*32 + rb*16 + row)*320 + g8;
    adst[q] = (short*)As + fr*512 + lane*8;
  }

  f32x4 acc[3][2][2];
  #pragma unroll
  for (int kr = 0; kr < 3; ++kr)
    #pragma unroll
    for (int r = 0; r < 2; ++r)
      #pragma unroll
      for (int s = 0; s < 2; ++s)
        acc[kr][r][s] = (f32x4){0.f, 0.f, 0.f, 0.f};

  {
    int4 v0 = *(const int4*)(asrc[0]);
    int4 v1 = *(const int4*)(asrc[1]);
    int4 v2 = *(const int4*)(asrc[2]);
    *(int4*)(adst[0]) = v0;
    *(int4*)(adst[1]) = v1;
    *(int4*)(adst[2]) = v2;
  }
  __syncthreads();

  int cur = 0;
  for (int c = 0; c < 10; ++c) {
    int4 v0, v1, v2;
    if (c < 9) {
      v0 = *(const int4*)(asrc[0] + (c+1)*32);
      v1 = *(const int4*)(asrc[1] + (c+1)*32);
      v2 = *(const int4*)(asrc[2] + (c+1)*32);
    }
    const int kk = c*32 + g8;
    bf16x8 BH0 = *(const bf16x8*)(entH + b0 + kk);
    bf16x8 BH1 = *(const bf16x8*)(entH + b1 + kk);
    bf16x8 BL0 = *(const bf16x8*)(entL + b0 + kk);
    bf16x8 BL1 = *(const bf16x8*)(entL + b1 + kk);

    const short* Ab = (const short*)As + cur*12*512 + lane*8;
    #pragma unroll
    for (int kr = 0; kr < 3; ++kr) {
      bf16x8 AH0 = *(const bf16x8*)(Ab + (kr*2 + 0)*512);
      bf16x8 AH1 = *(const bf16x8*)(Ab + (kr*2 + 1)*512);
      bf16x8 AL0 = *(const bf16x8*)(Ab + (6 + kr*2 + 0)*512);
      bf16x8 AL1 = *(const bf16x8*)(Ab + (6 + kr*2 + 1)*512);
      acc[kr][0][0] = __builtin_amdgcn_mfma_f32_16x16x32_bf16(AH0, BH0, acc[kr][0][0], 0, 0, 0);
      acc[kr][0][0] = __builtin_amdgcn_mfma_f32_16x16x32_bf16(AH0, BL0, acc[kr][0][0], 0, 0, 0);
      acc[kr][0][0] = __builtin_amdgcn_mfma_f32_16x16x32_bf16(AL0, BH0, acc[kr][0][0], 0, 0, 0);
      acc[kr][0][1] = __builtin_amdgcn_mfma_f32_16x16x32_bf16(AH0, BH1, acc[kr][0][1], 0, 0, 0);
      acc[kr][0][1] = __builtin_amdgcn_mfma_f32_16x16x32_bf16(AH0, BL1, acc[kr][0][1], 0, 0, 0);
      acc[kr][0][1] = __builtin_amdgcn_mfma_f32_16x16x32_bf16(AL0, BH1, acc[kr][0][1], 0, 0, 0);
      acc[kr][1][0] = __builtin_amdgcn_mfma_f32_16x16x32_bf16(AH1, BH0, acc[kr][1][0], 0, 0, 0);
      acc[kr][1][0] = __builtin_amdgcn_mfma_f32_16x16x32_bf16(AH1, BL0, acc[kr][1][0], 0, 0, 0);
      acc[kr][1][0] = __builtin_amdgcn_mfma_f32_16x16x32_bf16(AL1, BH0, acc[kr][1][0], 0, 0, 0);
      acc[kr][1][1] = __builtin_amdgcn_mfma_f32_16x16x32_bf16(AH1, BH1, acc[kr][1][1], 0, 0, 0);
      acc[kr][1][1] = __builtin_amdgcn_mfma_f32_16x16x32_bf16(AH1, BL1, acc[kr][1][1], 0, 0, 0);
      acc[kr][1][1] = __builtin_amdgcn_mfma_f32_16x16x32_bf16(AL1, BH1, acc[kr][1][1], 0, 0, 0);
    }

    if (c < 9) {
      short* dst = (short*)As + (cur^1)*12*512;
      *(int4*)(dst + (3*wave + 0)*512 + lane*8) = v0;
      *(int4*)(dst + (3*wave + 1)*512 + lane*8) = v1;
      *(int4*)(dst + (3*wave + 2)*512 + lane*8) = v2;
      __syncthreads();
      cur ^= 1;
    }
  }

  float* ph = phi + (i*MM + j)*CC*CC;
  const int rbase = (lane >> 4) * 4;
  #pragma unroll
  for (int r = 0; r < 2; ++r) {
    #pragma unroll
    for (int t = 0; t < 4; ++t) {
      const int p = 16*r + rbase + t;
      if (p < CC) {
        #pragma unroll
        for (int s = 0; s < 2; ++s) {
          const int q = 16*s + row;
          if (q < CC) {
            float v = a0*acc[0][r][s][t] + a1*acc[1][r][s][t] + a2*acc[2][r][s][t];
            ph[p*CC + q] = v;
          }
        }
      }
    }
  }
}

// ---------- zero ----------
__global__ void k_zero(float* __restrict__ p, int n) {
  int idx = blockIdx.x*256 + threadIdx.x;
  if (idx < n) p[idx] = 0.f;
}

// ---------- damped LBP update + fused stot (atomics) — R11-verified ----------
__global__ __launch_bounds__(256) void k_up4(const float* __restrict__ phi,
                                             const float* __restrict__ psi,
                                             const float* __restrict__ stot_cur,
                                             float* __restrict__ stot_next,
                                             const float* __restrict__ mb_old,
                                             float* __restrict__ mb_new) {
  const int i  = blockIdx.x / 25;
  const int jg = blockIdx.x % 25;
  const int wave = threadIdx.x >> 6;
  const int lane = threadIdx.x & 63;
  const int j = jg*4 + wave;
  const int half = lane >> 5;
  const int q = lane & 31;

  __shared__ float psi_st[32];
  if (threadIdx.x < CC)
    psi_st[threadIdx.x] = psi[i*CC + threadIdx.x] + stot_cur[i*CC + threadIdx.x];
  __syncthreads();

  float csr = (q < CC) ? psi_st[q] - mb_old[(j*MM + i)*CC + q] : -1e30f;

  const float* ph = phi + (i*MM + j)*CC*CC;
  float mv = -1e30f;
  const int p0 = half * 15;
  #pragma unroll
  for (int pp = 0; pp < 15; ++pp) {
    const int p = p0 + pp;
    float v = (q < CC) ? ph[p*CC + q] : -1e30f;
    float cv = __shfl(csr, p, 64);
    mv = fmaxf(mv, v + cv);
  }
  mv = fmaxf(mv, __shfl_xor(mv, 32, 64));
  float x = (q < CC) ? fmaxf(mv, 0.f) : -1e30f;

  float mx = x;
  #pragma unroll
  for (int off = 16; off; off >>= 1) mx = fmaxf(mx, __shfl_xor(mx, off, 64));
  float e = (q < CC) ? expf(x - mx) : 0.f;
  float se = e;
  #pragma unroll
  for (int off = 16; off; off >>= 1) se += __shfl_xor(se, off, 64);

  if (lane < CC) {
    float sm = e / se;
    float old = mb_old[(i*MM + j)*CC + lane];
    float nv = logf(0.5f*expf(old) + 0.5f*sm);
    mb_new[(i*MM + j)*CC + lane] = nv;
    atomicAdd(stot_next + j*CC + lane, nv);
  }
}

// ---------- out[i,:] = softmax( psi + stot_final[i,:] - mbar[i,i,:] ) ----------
__global__ __launch_bounds__(64) void k_final(const float* __restrict__ psi,
                                              const float* __restrict__ stotN,
                                              const float* __restrict__ mb,
                                              float* __restrict__ out) {
  int i = blockIdx.x;
  int lane = threadIdx.x;
  float x = -1e30f;
  if (lane < CC)
    x = psi[i*CC + lane] + stotN[i*CC + lane] - mb[(i*MM + i)*CC + lane];
  float mx = x;
  #pragma unroll
  for (int off = 16; off; off >>= 1) mx = fmaxf(mx, __shfl_xor(mx, off, 32));
  float e = (lane < CC) ? expf(x - mx) : 0.f;
  float se = e;
  #pragma unroll
  for (int off = 16; off; off >>= 1) se += __shfl_xor(se, off, 32);
  if (lane < CC) out[i*CC + lane] = e / se;
}

extern "C" void kernel_launch(void* const* d_in, const int* in_sizes, int n_in,
                              void* d_out, int out_size, void* d_ws, size_t ws_size,
                              hipStream_t stream) {
  (void)in_sizes; (void)n_in; (void)out_size; (void)ws_size;
  const float* ent  = (const float*)d_in[0];
  const float* fmc  = (const float*)d_in[1];
  const float* W    = (const float*)d_in[2];
  const float* b    = (const float*)d_in[3];
  const float* Bm   = (const float*)d_in[4];
  const float* R    = (const float*)d_in[5];
  const float* Dm   = (const float*)d_in[6];
  float* out = (float*)d_out;
  float* ws  = (float*)d_ws;

  float* f    = ws + 0;
  float* psi  = ws + 60000;
  float* t    = ws + 63000;
  float* a    = ws + 153000;
  short* REH  = (short*)(ws + 183000);
  short* REL  = (short*)(ws + 1719000);
  short* entH = (short*)(ws + 3255000);
  short* entL = (short*)(ws + 3767000);
  float* phi  = ws + 4279000;
  float* mbA  = ws + 13279000;
  float* mbB  = ws + 13579000;
  float* stotbuf = ws + 13879000;   // (NLOOP+1)*3000 floats
  float* gst  = ws + 183000;        // transient g stash (REH area, pre-k_re)

  k_zero<<<(633000 + 255)/256, 256, 0, stream>>>(mbA, 633000);
  k_zero<<<(30000 + 255)/256, 256, 0, stream>>>(f, 30000);   // f accumulated via atomics

  k_f1  <<<1200, 256, 0, stream>>>(fmc, W, b, f);
  k_tanh<<<(30000 + 255)/256, 256, 0, stream>>>(f, 30000);
  k_gt  <<<1900, 256, 0, stream>>>(Bm, Dm, f, gst, t);
  k_psi <<<MM, 256, 0, stream>>>(ent, gst, psi);
  k_a   <<<MM, 256, 0, stream>>>(f, t, a);
  k_esplit<<<MM, 256, 0, stream>>>(ent, entH, entL);

  k_zero<<<(3072000 + 255)/256, 256, 0, stream>>>(ws + 183000, 3072000);  // RE pads (after gst consumed)
  {
    dim3 grid(5, 24, 3);
    k_re<<<grid, 256, 0, stream>>>(R, ent, REH, REL);
  }
  k_phi6<<<2500, 256, 0, stream>>>(a, REH, REL, entH, entL, phi);

  float* cur = mbA; float* nxt = mbB;
  for (int it = 0; it < NLOOP; ++it) {
    k_up4<<<MM*25, 256, 0, stream>>>(phi, psi,
                                     stotbuf + it*MM*CC,
                                     stotbuf + (it+1)*MM*CC,
                                     cur, nxt);
    float* tmp = cur; cur = nxt; nxt = tmp;
  }
  k_final<<<MM, 64, 0, stream>>>(psi, stotbuf + NLOOP*MM*CC, cur, out);
}

// Round 14
// 447.506 us; speedup vs baseline: 2.1625x; 1.2325x over previous
//
#include <hip/hip_runtime.h>
#include <math.h>

#define MM 100     // mentions
#define CC 30      // candidates
#define DE 300     // embedding dim
#define NK 3       // relation types
#define NLOOP 10   // LBP iterations
#define INV_SQRT_D 0.05773502691896258f   // 1/sqrt(300)

typedef __attribute__((ext_vector_type(8))) short bf16x8;
typedef __attribute__((ext_vector_type(4))) float f32x4;

// ws layout (floats):
//  f@0 psi@60000 t@63000 a@153000
//  REH@183000 REL@1719000 (bf16 [k][i][32][320] padded hi/lo)
//  entH@3255000 entL@3767000 (bf16 [j][32][320])
//  phi@4279000  mbarA@13279000 mbarB@13579000 stotbuf@13879000 (11*3000)
//  g stash: transient at ws+183000 (REH area; consumed by k_psi2 before k_re)

__device__ inline void bf16split(float x, short* hi, short* lo) {
  unsigned u  = __float_as_uint(x);
  unsigned hu = u & 0xFFFF0000u;
  float xh = __uint_as_float(hu);
  float rl = x - xh;
  unsigned lu = __float_as_uint(rl);
  lu += 0x7FFFu + ((lu >> 16) & 1u);
  *hi = (short)(hu >> 16);
  *lo = (short)(lu >> 16);
}

// ---------- f partial GEMV: 1200 blocks (m x 12 e-chunks of 75), atomic ----------
__global__ __launch_bounds__(256) void k_f1(const float* __restrict__ fmc,
                                            const float* __restrict__ W,
                                            const float* __restrict__ b,
                                            float* __restrict__ f) {
  __shared__ float xs[75];
  const int m  = blockIdx.x / 12;
  const int eq = blockIdx.x % 12;
  const int e0 = eq * 75;
  const int tid = threadIdx.x;
  for (int e = tid; e < 75; e += 256) xs[e] = fmc[m*3*DE + e0 + e];
  __syncthreads();

  const int d0 = tid;
  const int d1 = tid + 256;
  float acc0 = 0.f, acc1 = 0.f;
  for (int e = 0; e < 75; ++e) {
    const float xv = xs[e];
    const float* Wr = W + (e0 + e)*DE;
    acc0 = fmaf(xv, Wr[d0], acc0);
    if (d1 < DE) acc1 = fmaf(xv, Wr[d1], acc1);
  }
  if (eq == 0) {
    acc0 += b[d0];
    if (d1 < DE) acc1 += b[d1];
  }
  atomicAdd(f + m*DE + d0, acc0);
  if (d1 < DE) atomicAdd(f + m*DE + d1, acc1);
}

// ---------- elementwise tanh over f ----------
__global__ void k_tanh(float* __restrict__ f, int n) {
  int idx = blockIdx.x*256 + threadIdx.x;
  if (idx < n) f[idx] = tanhf(f[idx]);
}

// ---------- g & t: wave-per-dot over stacked [B; D] rows, 1900 blocks ----------
__global__ __launch_bounds__(256) void k_gt(const float* __restrict__ Bm,
                                            const float* __restrict__ Dm,
                                            const float* __restrict__ f,
                                            float* __restrict__ gst,
                                            float* __restrict__ t) {
  __shared__ float fs[DE];
  const int m  = blockIdx.x / 19;
  const int cg = blockIdx.x % 19;
  const int wave = threadIdx.x >> 6, lane = threadIdx.x & 63;
  for (int e = threadIdx.x; e < DE; e += 256) fs[e] = f[m*DE + e];
  __syncthreads();

  #pragma unroll
  for (int u = 0; u < 16; ++u) {
    const int col = cg*64 + wave*16 + u;
    const bool ok = (col < 1200);
    const int ccl = ok ? col : 0;
    const float* row = (ccl < DE) ? (Bm + ccl*DE) : (Dm + (ccl - DE)*DE);
    float acc = 0.f;
    for (int e = lane; e < DE; e += 64) acc = fmaf(row[e], fs[e], acc);
    #pragma unroll
    for (int off = 32; off; off >>= 1) acc += __shfl_down(acc, off, 64);
    if (ok && lane == 0) {
      if (col < DE) {
        gst[m*DE + col] = acc;
      } else {
        const int k = (col - DE) / DE, d = (col - DE) % DE;
        t[(k*MM + m)*DE + d] = acc;
      }
    }
  }
}

// ---------- psi[m,c] = ent[m,c,:]·g[m,:]  (800 blocks, wave-per-c) ----------
__global__ __launch_bounds__(256) void k_psi2(const float* __restrict__ ent,
                                              const float* __restrict__ gst,
                                              float* __restrict__ psi) {
  __shared__ float gs[DE];
  const int m  = blockIdx.x >> 3;
  const int cg = blockIdx.x & 7;
  const int wave = threadIdx.x >> 6, lane = threadIdx.x & 63;
  for (int e = threadIdx.x; e < DE; e += 256) gs[e] = gst[m*DE + e];
  __syncthreads();
  const int c = cg*4 + wave;
  if (c < CC) {
    float acc = 0.f;
    const float* er = ent + (m*CC + c)*DE;
    for (int d = lane; d < DE; d += 64) acc = fmaf(er[d], gs[d], acc);
    #pragma unroll
    for (int off = 32; off; off >>= 1) acc += __shfl_down(acc, off, 64);
    if (lane == 0) psi[m*CC + c] = acc;
  }
}

// ---------- a[i,j,:] = softmax_k( f_i·t[k,j,:]/sqrt(D) )  (2500 blocks) ----------
__global__ __launch_bounds__(256) void k_a2(const float* __restrict__ f,
                                            const float* __restrict__ t,
                                            float* __restrict__ a) {
  __shared__ float fs[DE];
  const int i  = blockIdx.x / 25;
  const int jg = blockIdx.x % 25;
  const int wave = threadIdx.x >> 6, lane = threadIdx.x & 63;
  for (int e = threadIdx.x; e < DE; e += 256) fs[e] = f[i*DE + e];
  __syncthreads();
  const int j = jg*4 + wave;
  float sk[NK];
  #pragma unroll
  for (int k = 0; k < NK; ++k) {
    float acc = 0.f;
    const float* tr = t + (k*MM + j)*DE;
    for (int d = lane; d < DE; d += 64) acc = fmaf(fs[d], tr[d], acc);
    #pragma unroll
    for (int off = 32; off; off >>= 1) acc += __shfl_down(acc, off, 64);
    sk[k] = acc;
  }
  if (lane == 0) {
    float s0 = sk[0]*INV_SQRT_D, s1 = sk[1]*INV_SQRT_D, s2 = sk[2]*INV_SQRT_D;
    float mx = fmaxf(s0, fmaxf(s1, s2));
    float e0 = expf(s0 - mx), e1 = expf(s1 - mx), e2 = expf(s2 - mx);
    float inv = 1.f / (e0 + e1 + e2);
    float* ar = a + (i*MM + j)*NK;
    ar[0] = e0*inv; ar[1] = e1*inv; ar[2] = e2*inv;
  }
}

// ---------- split ent -> padded bf16 hi/lo [j][32][320] ----------
__global__ __launch_bounds__(256) void k_esplit(const float* __restrict__ ent,
                                                short* __restrict__ entH,
                                                short* __restrict__ entL) {
  int j = blockIdx.x;
  for (int idx = threadIdx.x; idx < 32*320; idx += 256) {
    int q = idx / 320, kk = idx % 320;
    float x = (q < CC && kk < DE) ? ent[(j*CC + q)*DE + kk] : 0.f;
    short h, l;
    bf16split(x, &h, &l);
    entH[(j*32 + q)*320 + kk] = h;
    entL[(j*32 + q)*320 + kk] = l;
  }
}

// ---------- RE GEMM: out = split_bf16( ent_flat[3000,300] @ R_k^T ), padded ----------
__global__ __launch_bounds__(256) void k_re(const float* __restrict__ R,
                                            const float* __restrict__ ent,
                                            short* __restrict__ REH,
                                            short* __restrict__ REL) {
  __shared__ float4 As4[128*5];
  __shared__ float4 Bs4[64*5];
  float* As = (float*)As4;
  float* Bs = (float*)Bs4;

  const int k  = blockIdx.z;
  const int r0 = blockIdx.y * 128;
  const int d0 = blockIdx.x * 64;
  const int tx = threadIdx.x & 15;
  const int ty = threadIdx.x >> 4;
  const float* A  = ent;
  const float* Bk = R + k*DE*DE;

  float acc[8][4];
  #pragma unroll
  for (int r = 0; r < 8; ++r)
    #pragma unroll
    for (int s = 0; s < 4; ++s) acc[r][s] = 0.f;

  for (int e0 = 0; e0 < DE; e0 += 20) {
    #pragma unroll
    for (int it = 0; it < 10; ++it) {
      int idx = threadIdx.x + it*256;
      int row = idx / 20, e = idx % 20;
      int gr = r0 + row;
      As[idx] = (gr < MM*CC) ? A[gr*DE + e0 + e] : 0.f;
    }
    #pragma unroll
    for (int it = 0; it < 5; ++it) {
      int idx = threadIdx.x + it*256;
      int row = idx / 20, e = idx % 20;
      int gd = d0 + row;
      Bs[idx] = (gd < DE) ? Bk[gd*DE + e0 + e] : 0.f;
    }
    __syncthreads();

    #pragma unroll
    for (int v = 0; v < 5; ++v) {
      float4 av[8], bv[4];
      #pragma unroll
      for (int r = 0; r < 8; ++r) av[r] = As4[(ty + 16*r)*5 + v];
      #pragma unroll
      for (int s = 0; s < 4; ++s) bv[s] = Bs4[(tx + 16*s)*5 + v];
      #pragma unroll
      for (int r = 0; r < 8; ++r)
        #pragma unroll
        for (int s = 0; s < 4; ++s) {
          acc[r][s] = fmaf(av[r].x, bv[s].x, acc[r][s]);
          acc[r][s] = fmaf(av[r].y, bv[s].y, acc[r][s]);
          acc[r][s] = fmaf(av[r].z, bv[s].z, acc[r][s]);
          acc[r][s] = fmaf(av[r].w, bv[s].w, acc[r][s]);
        }
    }
    __syncthreads();
  }

  #pragma unroll
  for (int r = 0; r < 8; ++r) {
    int gr = r0 + ty + 16*r;
    if (gr < MM*CC) {
      int i = gr / CC, p = gr % CC;
      #pragma unroll
      for (int s = 0; s < 4; ++s) {
        int gd = d0 + tx + 16*s;
        if (gd < DE) {
          size_t idx = (((size_t)k*MM + i)*32 + p)*320 + gd;
          short h, l;
          bf16split(acc[r][s], &h, &l);
          REH[idx] = h;
          REL[idx] = l;
        }
      }
    }
  }
}

// ---------- phi via MFMA: LDS-staged A (R11-verified k_phi6, frozen) ----------
__global__ __launch_bounds__(256) void k_phi6(const float* __restrict__ a,
                                              const short* __restrict__ REH,
                                              const short* __restrict__ REL,
                                              const short* __restrict__ entH,
                                              const short* __restrict__ entL,
                                              float* __restrict__ phi) {
  __shared__ short As[2][12*512];   // 24,576 B
  const int bs = blockIdx.x;
  int i, jg;
  if (bs < 2400) {
    int x = bs & 7;
    int s = bs >> 3;
    jg = s / 12;
    i  = x*12 + s % 12;
  } else {
    int r = bs - 2400;
    i  = 96 + (r & 3);
    jg = r >> 2;
  }
  const int wave = threadIdx.x >> 6;
  const int lane = threadIdx.x & 63;
  const int j = jg*4 + wave;

  const int row = lane & 15;
  const int g8  = (lane >> 4) << 3;

  const float a0 = a[(i*MM + j)*NK + 0];
  const float a1 = a[(i*MM + j)*NK + 1];
  const float a2 = a[(i*MM + j)*NK + 2];

  const int b0 = (j*32 + row)*320;
  const int b1 = b0 + 16*320;

  const short* asrc[3];
  short* adst[3];
  #pragma unroll
  for (int q = 0; q < 3; ++q) {
    const int fr = 3*wave + q;
    const int b6 = fr % 6;
    const int kr = b6 >> 1, rb = b6 & 1;
    const short* src = (fr < 6) ? REH : REL;
    asrc[q] = src + ((kr*MM + i)*32 + rb*16 + row)*320 + g8;
    adst[q] = (short*)As + fr*512 + lane*8;
  }

  f32x4 acc[3][2][2];
  #pragma unroll
  for (int kr = 0; kr < 3; ++kr)
    #pragma unroll
    for (int r = 0; r < 2; ++r)
      #pragma unroll
      for (int s = 0; s < 2; ++s)
        acc[kr][r][s] = (f32x4){0.f, 0.f, 0.f, 0.f};

  {
    int4 v0 = *(const int4*)(asrc[0]);
    int4 v1 = *(const int4*)(asrc[1]);
    int4 v2 = *(const int4*)(asrc[2]);
    *(int4*)(adst[0]) = v0;
    *(int4*)(adst[1]) = v1;
    *(int4*)(adst[2]) = v2;
  }
  __syncthreads();

  int cur = 0;
  for (int c = 0; c < 10; ++c) {
    int4 v0, v1, v2;
    if (c < 9) {
      v0 = *(const int4*)(asrc[0] + (c+1)*32);
      v1 = *(const int4*)(asrc[1] + (c+1)*32);
      v2 = *(const int4*)(asrc[2] + (c+1)*32);
    }
    const int kk = c*32 + g8;
    bf16x8 BH0 = *(const bf16x8*)(entH + b0 + kk);
    bf16x8 BH1 = *(const bf16x8*)(entH + b1 + kk);
    bf16x8 BL0 = *(const bf16x8*)(entL + b0 + kk);
    bf16x8 BL1 = *(const bf16x8*)(entL + b1 + kk);

    const short* Ab = (const short*)As + cur*12*512 + lane*8;
    #pragma unroll
    for (int kr = 0; kr < 3; ++kr) {
      bf16x8 AH0 = *(const bf16x8*)(Ab + (kr*2 + 0)*512);
      bf16x8 AH1 = *(const bf16x8*)(Ab + (kr*2 + 1)*512);
      bf16x8 AL0 = *(const bf16x8*)(Ab + (6 + kr*2 + 0)*512);
      bf16x8 AL1 = *(const bf16x8*)(Ab + (6 + kr*2 + 1)*512);
      acc[kr][0][0] = __builtin_amdgcn_mfma_f32_16x16x32_bf16(AH0, BH0, acc[kr][0][0], 0, 0, 0);
      acc[kr][0][0] = __builtin_amdgcn_mfma_f32_16x16x32_bf16(AH0, BL0, acc[kr][0][0], 0, 0, 0);
      acc[kr][0][0] = __builtin_amdgcn_mfma_f32_16x16x32_bf16(AL0, BH0, acc[kr][0][0], 0, 0, 0);
      acc[kr][0][1] = __builtin_amdgcn_mfma_f32_16x16x32_bf16(AH0, BH1, acc[kr][0][1], 0, 0, 0);
      acc[kr][0][1] = __builtin_amdgcn_mfma_f32_16x16x32_bf16(AH0, BL1, acc[kr][0][1], 0, 0, 0);
      acc[kr][0][1] = __builtin_amdgcn_mfma_f32_16x16x32_bf16(AL0, BH1, acc[kr][0][1], 0, 0, 0);
      acc[kr][1][0] = __builtin_amdgcn_mfma_f32_16x16x32_bf16(AH1, BH0, acc[kr][1][0], 0, 0, 0);
      acc[kr][1][0] = __builtin_amdgcn_mfma_f32_16x16x32_bf16(AH1, BL0, acc[kr][1][0], 0, 0, 0);
      acc[kr][1][0] = __builtin_amdgcn_mfma_f32_16x16x32_bf16(AL1, BH0, acc[kr][1][0], 0, 0, 0);
      acc[kr][1][1] = __builtin_amdgcn_mfma_f32_16x16x32_bf16(AH1, BH1, acc[kr][1][1], 0, 0, 0);
      acc[kr][1][1] = __builtin_amdgcn_mfma_f32_16x16x32_bf16(AH1, BL1, acc[kr][1][1], 0, 0, 0);
      acc[kr][1][1] = __builtin_amdgcn_mfma_f32_16x16x32_bf16(AL1, BH1, acc[kr][1][1], 0, 0, 0);
    }

    if (c < 9) {
      short* dst = (short*)As + (cur^1)*12*512;
      *(int4*)(dst + (3*wave + 0)*512 + lane*8) = v0;
      *(int4*)(dst + (3*wave + 1)*512 + lane*8) = v1;
      *(int4*)(dst + (3*wave + 2)*512 + lane*8) = v2;
      __syncthreads();
      cur ^= 1;
    }
  }

  float* ph = phi + (i*MM + j)*CC*CC;
  const int rbase = (lane >> 4) * 4;
  #pragma unroll
  for (int r = 0; r < 2; ++r) {
    #pragma unroll
    for (int t = 0; t < 4; ++t) {
      const int p = 16*r + rbase + t;
      if (p < CC) {
        #pragma unroll
        for (int s = 0; s < 2; ++s) {
          const int q = 16*s + row;
          if (q < CC) {
            float v = a0*acc[0][r][s][t] + a1*acc[1][r][s][t] + a2*acc[2][r][s][t];
            ph[p*CC + q] = v;
          }
        }
      }
    }
  }
}

// ---------- zero ----------
__global__ void k_zero(float* __restrict__ p, int n) {
  int idx = blockIdx.x*256 + threadIdx.x;
  if (idx < n) p[idx] = 0.f;
}

// ---------- damped LBP update + fused stot (atomics) — R11-verified ----------
__global__ __launch_bounds__(256) void k_up4(const float* __restrict__ phi,
                                             const float* __restrict__ psi,
                                             const float* __restrict__ stot_cur,
                                             float* __restrict__ stot_next,
                                             const float* __restrict__ mb_old,
                                             float* __restrict__ mb_new) {
  const int i  = blockIdx.x / 25;
  const int jg = blockIdx.x % 25;
  const int wave = threadIdx.x >> 6;
  const int lane = threadIdx.x & 63;
  const int j = jg*4 + wave;
  const int half = lane >> 5;
  const int q = lane & 31;

  __shared__ float psi_st[32];
  if (threadIdx.x < CC)
    psi_st[threadIdx.x] = psi[i*CC + threadIdx.x] + stot_cur[i*CC + threadIdx.x];
  __syncthreads();

  float csr = (q < CC) ? psi_st[q] - mb_old[(j*MM + i)*CC + q] : -1e30f;

  const float* ph = phi + (i*MM + j)*CC*CC;
  float mv = -1e30f;
  const int p0 = half * 15;
  #pragma unroll
  for (int pp = 0; pp < 15; ++pp) {
    const int p = p0 + pp;
    float v = (q < CC) ? ph[p*CC + q] : -1e30f;
    float cv = __shfl(csr, p, 64);
    mv = fmaxf(mv, v + cv);
  }
  mv = fmaxf(mv, __shfl_xor(mv, 32, 64));
  float x = (q < CC) ? fmaxf(mv, 0.f) : -1e30f;

  float mx = x;
  #pragma unroll
  for (int off = 16; off; off >>= 1) mx = fmaxf(mx, __shfl_xor(mx, off, 64));
  float e = (q < CC) ? expf(x - mx) : 0.f;
  float se = e;
  #pragma unroll
  for (int off = 16; off; off >>= 1) se += __shfl_xor(se, off, 64);

  if (lane < CC) {
    float sm = e / se;
    float old = mb_old[(i*MM + j)*CC + lane];
    float nv = logf(0.5f*expf(old) + 0.5f*sm);
    mb_new[(i*MM + j)*CC + lane] = nv;
    atomicAdd(stot_next + j*CC + lane, nv);
  }
}

// ---------- out[i,:] = softmax( psi + stot_final[i,:] - mbar[i,i,:] ) ----------
__global__ __launch_bounds__(64) void k_final(const float* __restrict__ psi,
                                              const float* __restrict__ stotN,
                                              const float* __restrict__ mb,
                                              float* __restrict__ out) {
  int i = blockIdx.x;
  int lane = threadIdx.x;
  float x = -1e30f;
  if (lane < CC)
    x = psi[i*CC + lane] + stotN[i*CC + lane] - mb[(i*MM + i)*CC + lane];
  float mx = x;
  #pragma unroll
  for (int off = 16; off; off >>= 1) mx = fmaxf(mx, __shfl_xor(mx, off, 32));
  float e = (lane < CC) ? expf(x - mx) : 0.f;
  float se = e;
  #pragma unroll
  for (int off = 16; off; off >>= 1) se += __shfl_xor(se, off, 32);
  if (lane < CC) out[i*CC + lane] = e / se;
}

extern "C" void kernel_launch(void* const* d_in, const int* in_sizes, int n_in,
                              void* d_out, int out_size, void* d_ws, size_t ws_size,
                              hipStream_t stream) {
  (void)in_sizes; (void)n_in; (void)out_size; (void)ws_size;
  const float* ent  = (const float*)d_in[0];
  const float* fmc  = (const float*)d_in[1];
  const float* W    = (const float*)d_in[2];
  const float* b    = (const float*)d_in[3];
  const float* Bm   = (const float*)d_in[4];
  const float* R    = (const float*)d_in[5];
  const float* Dm   = (const float*)d_in[6];
  float* out = (float*)d_out;
  float* ws  = (float*)d_ws;

  float* f    = ws + 0;
  float* psi  = ws + 60000;
  float* t    = ws + 63000;
  float* a    = ws + 153000;
  short* REH  = (short*)(ws + 183000);
  short* REL  = (short*)(ws + 1719000);
  short* entH = (short*)(ws + 3255000);
  short* entL = (short*)(ws + 3767000);
  float* phi  = ws + 4279000;
  float* mbA  = ws + 13279000;
  float* mbB  = ws + 13579000;
  float* stotbuf = ws + 13879000;   // (NLOOP+1)*3000 floats
  float* gst  = ws + 183000;        // transient g stash (REH area, pre-k_re)

  k_zero<<<(633000 + 255)/256, 256, 0, stream>>>(mbA, 633000);
  k_zero<<<(30000 + 255)/256, 256, 0, stream>>>(f, 30000);   // f accumulated via atomics

  k_f1  <<<1200, 256, 0, stream>>>(fmc, W, b, f);
  k_tanh<<<(30000 + 255)/256, 256, 0, stream>>>(f, 30000);
  k_gt  <<<1900, 256, 0, stream>>>(Bm, Dm, f, gst, t);
  k_psi2<<<MM*8, 256, 0, stream>>>(ent, gst, psi);
  k_a2  <<<MM*25, 256, 0, stream>>>(f, t, a);
  k_esplit<<<MM, 256, 0, stream>>>(ent, entH, entL);

  k_zero<<<(3072000 + 255)/256, 256, 0, stream>>>(ws + 183000, 3072000);  // RE pads (after gst consumed)
  {
    dim3 grid(5, 24, 3);
    k_re<<<grid, 256, 0, stream>>>(R, ent, REH, REL);
  }
  k_phi6<<<2500, 256, 0, stream>>>(a, REH, REL, entH, entL, phi);

  float* cur = mbA; float* nxt = mbB;
  for (int it = 0; it < NLOOP; ++it) {
    k_up4<<<MM*25, 256, 0, stream>>>(phi, psi,
                                     stotbuf + it*MM*CC,
                                     stotbuf + (it+1)*MM*CC,
                                     cur, nxt);
    float* tmp = cur; cur = nxt; nxt = tmp;
  }
  k_final<<<MM, 64, 0, stream>>>(psi, stotbuf + NLOOP*MM*CC, cur, out);
}